// Round 5
// baseline (129.354 us; speedup 1.0000x reference)
//
#include <hip/hip_runtime.h>
#include <hip/hip_bf16.h>

#define N 8192
#define FIN 128
#define FOUT 64
#define CSPLIT 2
#define CHUNK (N / CSPLIT)     // 4096 cols per block
#define WCOLS (CHUNK / 4)      // 1024 cols per wave
#define STEPS (WCOLS / 32)     // 32 steps of 32 cols

typedef __attribute__((ext_vector_type(4))) float f32x4;
typedef __attribute__((ext_vector_type(4))) int i32x4;
typedef __attribute__((ext_vector_type(8))) short bf16x8;

#define GLOAD_LDS16(gp, lp)                                                    \
    __builtin_amdgcn_global_load_lds(                                          \
        (const __attribute__((address_space(1))) void*)(gp),                   \
        (__attribute__((address_space(3))) void*)(lp), 16, 0, 0)

__device__ __forceinline__ short f2bf(float x) {
    __hip_bfloat16 b = __float2bfloat16(x);
    union { __hip_bfloat16 b; short s; } u; u.b = b; return u.s;
}

// Kernel 1: Wh = h @ W (store transposed bf16), s_src = Wh@a1, s_dst = Wh@a2
__global__ __launch_bounds__(256) void wh_kernel(
    const float* __restrict__ h, const float* __restrict__ W,
    const float* __restrict__ a,
    __hip_bfloat16* __restrict__ whT, float* __restrict__ s_src,
    float* __restrict__ s_dst) {
    const int wave = threadIdx.x >> 6;
    const int lane = threadIdx.x & 63;   // lane = output feature f
    const int row = blockIdx.x * 4 + wave;
    const float* hr = h + (size_t)row * FIN;
    float acc = 0.f;
#pragma unroll 8
    for (int k = 0; k < FIN; ++k) {
        acc += hr[k] * W[k * FOUT + lane];
    }
    whT[(size_t)lane * N + row] = __float2bfloat16(acc);
    float s1 = acc * a[lane];
    float s2 = acc * a[FOUT + lane];
#pragma unroll
    for (int mm = 32; mm >= 1; mm >>= 1) {
        s1 += __shfl_xor(s1, mm, 64);
        s2 += __shfl_xor(s2, mm, 64);
    }
    if (lane == 0) { s_src[row] = s1; s_dst[row] = s2; }
}

// Kernel 2: each wave independently computes 16 rows x 1024 cols with an
// explicit asm load pipeline (adj depth-3, whT depth-2, manual vmcnt).
// Block = 4 waves (same 16 rows, 4 col-chunks of 1024). Grid = 512 rg * CSPLIT.
__global__ __launch_bounds__(256) void gat_partial(
    const int* __restrict__ adj, const __hip_bfloat16* __restrict__ whT,
    const float* __restrict__ s_src, const float* __restrict__ s_dst,
    float* __restrict__ numP, float* __restrict__ denP) {
    __shared__ union SMem {
        float sdl[CHUNK];                                      // 16 KB
        struct { float pC[4][16][FOUT]; float pD[4][16]; } e;  // 16.6 KB
    } sm;

    const int tid = threadIdx.x;
    const int w = tid >> 6, lane = tid & 63;
    const int m = lane & 15, kg = lane >> 4;
    const int rg = blockIdx.x >> 1;
    const int c = blockIdx.x & 1;
    const int ibase = rg * 16;
    const int cb = c * CHUNK;
    const int wb = cb + w * WCOLS;
    const float ssrc = s_src[ibase + m];

    // ---- stage s_dst chunk (16 KB) into LDS once ----
#pragma unroll
    for (int q = 0; q < 4; ++q) {
        const int j = 4 * w + q;
        GLOAD_LDS16(s_dst + cb + j * 256 + lane * 4, &sm.sdl[j * 256]);
    }
    asm volatile("s_waitcnt vmcnt(0)" ::: "memory");
    __syncthreads();

    // ---- pipeline registers ----
    i32x4 a0_0{}, a1_0{}, a0_1{}, a1_1{}, a0_2{}, a1_2{};
    bf16x8 b0_0{}, b1_0{}, b2_0{}, b3_0{}, b0_1{}, b1_1{}, b2_1{}, b3_1{};
    f32x4 acc0 = {0,0,0,0}, acc1 = {0,0,0,0}, acc2 = {0,0,0,0}, acc3 = {0,0,0,0};
    float dsum = 0.f;

    const int* ap = adj + (size_t)(ibase + m) * N + wb + kg * 8;
    const __hip_bfloat16* wp0 = whT + (size_t)(0 * 16 + m) * N + wb + kg * 8;
    const __hip_bfloat16* wp1 = whT + (size_t)(1 * 16 + m) * N + wb + kg * 8;
    const __hip_bfloat16* wp2 = whT + (size_t)(2 * 16 + m) * N + wb + kg * 8;
    const __hip_bfloat16* wp3 = whT + (size_t)(3 * 16 + m) * N + wb + kg * 8;

#define LD16(dst, ptr) \
    asm volatile("global_load_dwordx4 %0, %1, off" : "=v"(dst) : "v"(ptr))

#define ISSA(S, T) do {                     \
    LD16(a0_##S, ap + (T) * 32);            \
    LD16(a1_##S, ap + (T) * 32 + 4);        \
} while (0)

#define ISSW(S, T) do {                     \
    LD16(b0_##S, wp0 + (T) * 32);           \
    LD16(b1_##S, wp1 + (T) * 32);           \
    LD16(b2_##S, wp2 + (T) * 32);           \
    LD16(b3_##S, wp3 + (T) * 32);           \
} while (0)

#define WAITV(WN, S3, S2)                                                   \
    asm volatile("s_waitcnt vmcnt(" WN ")"                                  \
        : "+v"(a0_##S3), "+v"(a1_##S3), "+v"(b0_##S2), "+v"(b1_##S2),       \
          "+v"(b2_##S2), "+v"(b3_##S2))

#define COMPUTE(T, S3, S2) do {                                             \
    f32x4 d0 = *(const f32x4*)&sm.sdl[w * WCOLS + (T) * 32 + kg * 8];       \
    f32x4 d1 = *(const f32x4*)&sm.sdl[w * WCOLS + (T) * 32 + kg * 8 + 4];   \
    bf16x8 afr;                                                             \
    _Pragma("unroll") for (int e = 0; e < 4; ++e) {                         \
        float x = ssrc + d0[e];                                             \
        x = (x >= 0.f) ? x : 0.2f * x;                                      \
        float p = (a0_##S3[e] > 0) ? __expf(x) : 0.f;                       \
        dsum += p; afr[e] = f2bf(p);                                        \
    }                                                                       \
    _Pragma("unroll") for (int e = 0; e < 4; ++e) {                         \
        float x = ssrc + d1[e];                                             \
        x = (x >= 0.f) ? x : 0.2f * x;                                      \
        float p = (a1_##S3[e] > 0) ? __expf(x) : 0.f;                       \
        dsum += p; afr[4 + e] = f2bf(p);                                    \
    }                                                                       \
    acc0 = __builtin_amdgcn_mfma_f32_16x16x32_bf16(afr, b0_##S2, acc0, 0, 0, 0); \
    acc1 = __builtin_amdgcn_mfma_f32_16x16x32_bf16(afr, b1_##S2, acc1, 0, 0, 0); \
    acc2 = __builtin_amdgcn_mfma_f32_16x16x32_bf16(afr, b2_##S2, acc2, 0, 0, 0); \
    acc3 = __builtin_amdgcn_mfma_f32_16x16x32_bf16(afr, b3_##S2, acc3, 0, 0, 0); \
} while (0)

#define ITER(T, WN, S3, S2, DA, DW) do {    \
    WAITV(WN, S3, S2);                      \
    COMPUTE(T, S3, S2);                     \
    if (DA) ISSA(S3, (T) + 3);              \
    if (DW) ISSW(S2, (T) + 2);              \
} while (0)

    // prologue (FIFO: adj0, adj1, wh0, adj2, wh1)
    ISSA(0, 0); ISSA(1, 1); ISSW(0, 0); ISSA(2, 2); ISSW(1, 1);

    // steady state: T = 0..23 (slot pattern period 6)
    for (int tb = 0; tb < 24; tb += 6) {
        ITER(tb + 0, "6", 0, 0, true, true);
        ITER(tb + 1, "6", 1, 1, true, true);
        ITER(tb + 2, "6", 2, 0, true, true);
        ITER(tb + 3, "6", 0, 1, true, true);
        ITER(tb + 4, "6", 1, 0, true, true);
        ITER(tb + 5, "6", 2, 1, true, true);
    }
    // tail peel T = 24..31
    ITER(24, "6", 0, 0, true,  true);
    ITER(25, "6", 1, 1, true,  true);
    ITER(26, "6", 2, 0, true,  true);
    ITER(27, "6", 0, 1, true,  true);
    ITER(28, "6", 1, 0, true,  true);   // issues ADJ(31), WHT(30)
    ITER(29, "6", 2, 1, false, true);   // issues WHT(31)
    ITER(30, "4", 0, 0, false, false);
    ITER(31, "0", 1, 1, false, false);

#undef ITER
#undef COMPUTE
#undef WAITV
#undef ISSW
#undef ISSA
#undef LD16

    // denominator: lanes l, l^16, l^32, l^48 share row m
    dsum += __shfl_xor(dsum, 16, 64);
    dsum += __shfl_xor(dsum, 32, 64);

    __syncthreads();   // done with sdl; union reuse
#pragma unroll
    for (int r = 0; r < 4; ++r) {
        sm.e.pC[w][kg * 4 + r][0 * 16 + m] = acc0[r];
        sm.e.pC[w][kg * 4 + r][1 * 16 + m] = acc1[r];
        sm.e.pC[w][kg * 4 + r][2 * 16 + m] = acc2[r];
        sm.e.pC[w][kg * 4 + r][3 * 16 + m] = acc3[r];
    }
    if (kg == 0) sm.e.pD[w][m] = dsum;
    __syncthreads();

    float* numC = numP + (size_t)c * N * FOUT;
    float* denC = denP + (size_t)c * N;
#pragma unroll
    for (int k = 0; k < 4; ++k) {
        int idx = k * 256 + tid;
        int i = idx >> 6, f = idx & 63;
        float num = sm.e.pC[0][i][f] + sm.e.pC[1][i][f] + sm.e.pC[2][i][f] + sm.e.pC[3][i][f];
        numC[(size_t)(ibase + i) * FOUT + f] = num;
        if (f == 0) {
            denC[ibase + i] = sm.e.pD[0][i] + sm.e.pD[1][i] + sm.e.pD[2][i] + sm.e.pD[3][i];
        }
    }
}

// Kernel 3: sum chunk partials, divide, ELU, store.
__global__ __launch_bounds__(256) void gat_combine(
    const float* __restrict__ numP, const float* __restrict__ denP,
    float* __restrict__ out) {
    int idx = blockIdx.x * 256 + threadIdx.x;
    int row = idx >> 6;
    float num = 0.f, den = 0.f;
#pragma unroll
    for (int cc = 0; cc < CSPLIT; ++cc) {
        num += numP[(size_t)cc * N * FOUT + idx];
        den += denP[(size_t)cc * N + row];
    }
    float v = num / den;
    out[idx] = (v > 0.f) ? v : expm1f(v);
}

extern "C" void kernel_launch(void* const* d_in, const int* in_sizes, int n_in,
                              void* d_out, int out_size, void* d_ws, size_t ws_size,
                              hipStream_t stream) {
    const float* h = (const float*)d_in[0];
    const int* adj = (const int*)d_in[1];
    const float* W = (const float*)d_in[2];
    const float* a = (const float*)d_in[3];
    float* out = (float*)d_out;

    char* ws = (char*)d_ws;
    __hip_bfloat16* whT = (__hip_bfloat16*)ws;                       // 1 MB
    float* s_src = (float*)(ws + (size_t)FOUT * N * sizeof(__hip_bfloat16));
    float* s_dst = s_src + N;                                        // +64 KB
    float* numP = s_dst + N;                                         // 4 MB
    float* denP = numP + (size_t)CSPLIT * N * FOUT;                  // 64 KB

    hipLaunchKernelGGL(wh_kernel, dim3(N / 4), dim3(256), 0, stream,
                       h, W, a, whT, s_src, s_dst);
    hipLaunchKernelGGL(gat_partial, dim3((N / 16) * CSPLIT), dim3(256), 0, stream,
                       adj, whT, s_src, s_dst, numP, denP);
    hipLaunchKernelGGL(gat_combine, dim3(N * FOUT / 256), dim3(256), 0, stream,
                       numP, denP, out);
}